// Round 6
// baseline (188.977 us; speedup 1.0000x reference)
//
#include <hip/hip_runtime.h>

#define DEV __device__ __forceinline__

DEV int   f2i(float v){ return __builtin_bit_cast(int, v); }
DEV float i2f(int v){ return __builtin_bit_cast(float, v); }
DEV float blane(float v, int l){ return i2f(__builtin_amdgcn_readlane(f2i(v), l)); }

template<int C, int RM> DEV float dpp_add_m(float v){
  return v + i2f(__builtin_amdgcn_update_dpp(0, f2i(v), C, RM, 0xF, true));
}
template<int C, int RM> DEV float dpp_max_m(float v){
  return fmaxf(v, i2f(__builtin_amdgcn_update_dpp(0, f2i(v), C, RM, 0xF, true)));
}
// all-DPP wave64 reduction (no LDS ops): xor1,xor2,half_mirror,mirror give
// row(16) sums; row_bcast15 (rows 1,3) then row_bcast31 (rows 2,3) fold rows;
// lane 63 holds the total -> one readlane. ~40cy serial vs ~170cy w/ ds_swizzle.
DEV float wred_sum(float v){
  v = dpp_add_m<0xB1,0xF>(v); v = dpp_add_m<0x4E,0xF>(v);
  v = dpp_add_m<0x141,0xF>(v); v = dpp_add_m<0x140,0xF>(v);
  v = dpp_add_m<0x142,0xA>(v);   // row_bcast15 -> rows 1,3
  v = dpp_add_m<0x143,0xC>(v);   // row_bcast31 -> rows 2,3
  return blane(v, 63);
}
DEV float wred_max(float v){
  v = dpp_max_m<0xB1,0xF>(v); v = dpp_max_m<0x4E,0xF>(v);
  v = dpp_max_m<0x141,0xF>(v); v = dpp_max_m<0x140,0xF>(v);
  v = dpp_max_m<0x142,0xA>(v);
  v = dpp_max_m<0x143,0xC>(v);
  return blane(v, 63);
}

// shuffle helpers (k_sel)
DEV float wsum(float v){
  #pragma unroll
  for (int o = 32; o; o >>= 1) v += __shfl_xor(v, o, 64);
  return v;
}
DEV float wmax(float v){
  #pragma unroll
  for (int o = 32; o; o >>= 1) v = fmaxf(v, __shfl_xor(v, o, 64));
  return v;
}

// ---------------------------------------------------------------------------
// K1: per-batch token histogram + per-token QKV projection table.
// Block i: histogram of seq[i,:] (batch role) AND qkv row for token-id i
// (token role; B == V == 64). qkv_tab[tok][0:64]=q,[64:128]=k,[128:192]=v.
// Block 0 zeroes the output accumulator.
// ---------------------------------------------------------------------------
__global__ __launch_bounds__(1024) void k_prep(
    const int* __restrict__ seq, const float* __restrict__ embed,
    const float* __restrict__ wqkv, const float* __restrict__ bqkv,
    float* __restrict__ qkv_tab, float* __restrict__ cnt_f,
    float* __restrict__ out){
  const int b = blockIdx.x, tid = threadIdx.x;
  if (b == 0 && tid == 0) out[0] = 0.f;
  __shared__ float emb[64];
  __shared__ int hh[64];
  if (tid < 64){ emb[tid] = embed[b*64 + tid]; hh[tid] = 0; }
  __syncthreads();
  atomicAdd(&hh[seq[b*1024 + tid]], 1);
  if (tid < 192){
    const float4* w4 = (const float4*)(wqkv + tid*64);
    float a0 = bqkv[tid], a1 = 0.f, a2 = 0.f, a3 = 0.f;
    #pragma unroll
    for (int k = 0; k < 16; k += 4){
      float4 wa = w4[k],   wb = w4[k+1], wc = w4[k+2], wd = w4[k+3];
      a0 += wa.x*emb[4*k]    + wa.y*emb[4*k+1]  + wa.z*emb[4*k+2]  + wa.w*emb[4*k+3];
      a1 += wb.x*emb[4*k+4]  + wb.y*emb[4*k+5]  + wb.z*emb[4*k+6]  + wb.w*emb[4*k+7];
      a2 += wc.x*emb[4*k+8]  + wc.y*emb[4*k+9]  + wc.z*emb[4*k+10] + wc.w*emb[4*k+11];
      a3 += wd.x*emb[4*k+12] + wd.y*emb[4*k+13] + wd.z*emb[4*k+14] + wd.w*emb[4*k+15];
    }
    qkv_tab[b*192 + tid] = (a0+a1)+(a2+a3);
  }
  __syncthreads();
  if (tid < 64) cnt_f[b*64 + tid] = (float)hh[tid];
}

// ---------------------------------------------------------------------------
// K2: encoder table. hidden[b,l] depends only on (b, seq[b,l]) (no positional
// term -> softmax over L collapses to count-weighted sums over 64 token types).
// Grid: 256 = (batch = blk>>2, quarter = blk&3). Block: 512 thr = 8 waves.
// Each wave computes 2 tokens. DIAGNOSTIC: compute section repeated 2x
// (idempotent stores) to push k_enc above the 40us fill entries in the
// rocprof top-5 and recover its counters.
// ---------------------------------------------------------------------------
__global__ __launch_bounds__(512, 2) void k_enc(
    const float* __restrict__ qkv_tab, const float* __restrict__ cnt_f,
    const float* __restrict__ embed,
    const float* __restrict__ wo_attn, const float* __restrict__ bo_attn,
    const float* __restrict__ w_ff1, const float* __restrict__ b_ff1,
    const float* __restrict__ w_ff2, const float* __restrict__ b_ff2,
    const float* __restrict__ g1, const float* __restrict__ be1,
    const float* __restrict__ g2, const float* __restrict__ be2,
    const float* __restrict__ w_s1, const float* __restrict__ b_s1,
    const float* __restrict__ w_s2, const float* __restrict__ b_s2,
    float* __restrict__ hidden_tab, float* __restrict__ s2f_tab){
  const int b = blockIdx.x >> 2, quarter = blockIdx.x & 3;
  const int tid = threadIdx.x, w = tid >> 6, lane = tid & 63;

  __shared__ float4 k4 [64*16];    // K rows (token-major), swizzled slots
  __shared__ float4 v4t[64*16];    // V^T rows (dim-major), swizzled slots
  __shared__ float4 wo4[64*16];
  __shared__ float4 f14[128*16];
  __shared__ float4 f24[64*32];
  __shared__ float  cnt_lds[64];

  const float4* qkv4 = (const float4*)qkv_tab;
  const float4* wo_4 = (const float4*)wo_attn;
  const float4* f1_4 = (const float4*)w_ff1;
  const float4* f2_4 = (const float4*)w_ff2;
  float* v4f = (float*)v4t;

  #pragma unroll
  for (int ii = 0; ii < 2; ++ii){
    int i = tid + ii*512;
    int r = i >> 4, c4 = i & 15, s = c4 ^ (r & 15);
    k4 [r*16 + s] = qkv4[r*48 + 16 + c4];
    wo4[r*16 + s] = wo_4[i];
    float4 vv = qkv4[r*48 + 32 + c4];
    int d0 = 4*c4;
    v4f[(d0  )*64 + 4*((r>>2) ^ ((d0  )&15)) + (r&3)] = vv.x;
    v4f[(d0+1)*64 + 4*((r>>2) ^ ((d0+1)&15)) + (r&3)] = vv.y;
    v4f[(d0+2)*64 + 4*((r>>2) ^ ((d0+2)&15)) + (r&3)] = vv.z;
    v4f[(d0+3)*64 + 4*((r>>2) ^ ((d0+3)&15)) + (r&3)] = vv.w;
  }
  #pragma unroll
  for (int ii = 0; ii < 4; ++ii){
    int i = tid + ii*512;
    int r1 = i >> 4, c41 = i & 15;
    f14[r1*16 + (c41 ^ (r1 & 15))] = f1_4[i];
    int r2 = i >> 5, c42 = i & 31;
    f24[r2*32 + (c42 ^ (r2 & 15))] = f2_4[i];
  }
  if (tid < 64) cnt_lds[tid] = cnt_f[b*64 + tid];
  __syncthreads();

  const int   t0 = quarter*16 + w*2;
  const int   sw = lane & 15;
  const float cme  = cnt_lds[lane];
  const bool  pres = cme > 0.f;
  const float sc = 0.17677669529663687f;  // 1/sqrt(32)
  const float g1v=g1[lane], be1v=be1[lane], g2v=g2[lane], be2v=be2[lane];
  const float bov=bo_attn[lane], bf2v=b_ff2[lane];
  const float bf1a=b_ff1[lane], bf1b=b_ff1[64+lane];
  const float ws1v=w_s1[lane], ws2v=w_s2[lane];
  const float bs1=b_s1[0], bs2=b_s2[0];

  #pragma unroll 1
  for (int rep = 0; rep < 2; ++rep){
  // ---- scores: lane = key token; S[h][tok_t][lane] ----
  float q0 = qkv_tab[(t0+0)*192 + lane];
  float q1 = qkv_tab[(t0+1)*192 + lane];
  float sA[2] = {0.f,0.f}, sB[2] = {0.f,0.f};
  #pragma unroll
  for (int c4 = 0; c4 < 16; ++c4){
    float4 kk = k4[lane*16 + (c4 ^ sw)];
    #pragma unroll
    for (int j = 0; j < 4; ++j){
      const int d = 4*c4 + j;
      float ke = (j==0)?kk.x:(j==1)?kk.y:(j==2)?kk.z:kk.w;
      float b0 = blane(q0,d), b1 = blane(q1,d);
      if (d < 32){ sA[0]+=b0*ke; sA[1]+=b1*ke; }
      else       { sB[0]+=b0*ke; sB[1]+=b1*ke; }
    }
  }
  // ---- count-weighted softmax over token types ----
  float p0[2], p1[2], d0v[2], d1v[2];
  #pragma unroll
  for (int t = 0; t < 2; ++t){
    float s0 = sA[t]*sc, s1 = sB[t]*sc;
    float m0 = wred_max(pres ? s0 : -1e30f);
    float m1 = wred_max(pres ? s1 : -1e30f);
    p0[t] = pres ? cme*__expf(s0 - m0) : 0.f;
    p1[t] = pres ? cme*__expf(s1 - m1) : 0.f;
    d0v[t] = wred_sum(p0[t]);
    d1v[t] = wred_sum(p1[t]);
  }
  // ---- o[lane] = sum_t' p[h(lane)][t'] * v[t'][lane] (p bcast via readlane) --
  float o[2] = {0.f,0.f};
  #pragma unroll
  for (int c4 = 0; c4 < 16; ++c4){
    float4 vv = v4t[lane*16 + (c4 ^ sw)];
    #pragma unroll
    for (int j = 0; j < 4; ++j){
      const int tp = 4*c4 + j;
      float ve = (j==0)?vv.x:(j==1)?vv.y:(j==2)?vv.z:vv.w;
      float a0 = blane(p0[0],tp), a1 = blane(p1[0],tp);
      float b0 = blane(p0[1],tp), b1 = blane(p1[1],tp);
      o[0] += (lane < 32 ? a0 : a1) * ve;
      o[1] += (lane < 32 ? b0 : b1) * ve;
    }
  }
  #pragma unroll
  for (int t = 0; t < 2; ++t) o[t] /= (lane < 32 ? d0v[t] : d1v[t]);
  // ---- out-proj ----
  float aT[2] = {bov,bov};
  #pragma unroll
  for (int c4 = 0; c4 < 16; ++c4){
    float4 ww = wo4[lane*16 + (c4 ^ sw)];
    #pragma unroll
    for (int j = 0; j < 4; ++j){
      const int k = 4*c4 + j;
      float we = (j==0)?ww.x:(j==1)?ww.y:(j==2)?ww.z:ww.w;
      aT[0] += we*blane(o[0],k); aT[1] += we*blane(o[1],k);
    }
  }
  // ---- residual + LN1 ----
  float xn[2];
  #pragma unroll
  for (int t = 0; t < 2; ++t){
    float x = embed[(t0+t)*64 + lane] + aT[t];
    float mu = wred_sum(x) * 0.015625f;
    float xm = x - mu;
    float var = wred_sum(xm*xm) * 0.015625f;
    xn[t] = xm * rsqrtf(var + 1e-5f) * g1v + be1v;
  }
  // ---- FF1 + ReLU ----
  float y0[2] = {bf1a,bf1a}, y1[2] = {bf1b,bf1b};
  #pragma unroll
  for (int c4 = 0; c4 < 16; ++c4){
    float4 wA = f14[lane*16 + (c4 ^ sw)];
    float4 wB = f14[(lane+64)*16 + (c4 ^ sw)];
    #pragma unroll
    for (int j = 0; j < 4; ++j){
      const int k = 4*c4 + j;
      float wa = (j==0)?wA.x:(j==1)?wA.y:(j==2)?wA.z:wA.w;
      float wb = (j==0)?wB.x:(j==1)?wB.y:(j==2)?wB.z:wB.w;
      float x0 = blane(xn[0],k), x1 = blane(xn[1],k);
      y0[0]+=wa*x0; y0[1]+=wa*x1;
      y1[0]+=wb*x0; y1[1]+=wb*x1;
    }
  }
  #pragma unroll
  for (int t = 0; t < 2; ++t){ y0[t] = fmaxf(y0[t],0.f); y1[t] = fmaxf(y1[t],0.f); }
  // ---- FF2 ----
  float z[2] = {bf2v,bf2v};
  #pragma unroll
  for (int c4 = 0; c4 < 32; ++c4){
    float4 ww = f24[lane*32 + (c4 ^ sw)];
    #pragma unroll
    for (int j = 0; j < 4; ++j){
      const int jj = 4*c4 + j;
      float we = (j==0)?ww.x:(j==1)?ww.y:(j==2)?ww.z:ww.w;
      if (jj < 64){
        z[0]+=we*blane(y0[0],jj); z[1]+=we*blane(y0[1],jj);
      } else {
        z[0]+=we*blane(y1[0],jj-64); z[1]+=we*blane(y1[1],jj-64);
      }
    }
  }
  // ---- residual + LN2 + gates + store ----
  #pragma unroll
  for (int t = 0; t < 2; ++t){
    float r = xn[t] + z[t];
    float mu2 = wred_sum(r) * 0.015625f;
    float rm = r - mu2;
    float var2 = wred_sum(rm*rm) * 0.015625f;
    float hid = rm * rsqrtf(var2 + 1e-5f) * g2v + be2v;
    float t1 = wred_sum(hid * ws1v) + bs1;
    float t2 = wred_sum(hid * ws2v) + bs2;
    float sg1 = 1.f / (1.f + __expf(-t1));
    float sg2 = 1.f / (1.f + __expf(-t2));
    float s2f = (sg1 > 0.5f) ? sg2 : 0.f;
    hidden_tab[(b*64 + t0 + t)*64 + lane] = hid;
    if (lane == 0) s2f_tab[b*64 + t0 + t] = s2f;
  }
  }  // rep
}

// ---------------------------------------------------------------------------
// K3: per-batch top-6 selection (JAX top_k: value desc, index asc tie-break),
// memory reader, cross-entropy, atomic mean into out.
// 64 blocks x 256 threads: 4 waves stage weights cooperatively, wave 0 computes.
// ---------------------------------------------------------------------------
__global__ __launch_bounds__(256) void k_sel(
    const int* __restrict__ seq, const int* __restrict__ query,
    const int* __restrict__ target,
    const float* __restrict__ hidden_tab, const float* __restrict__ s2f_tab,
    const float* __restrict__ w_qr, const float* __restrict__ b_qr,
    const float* __restrict__ w_or, const float* __restrict__ b_or,
    const float* __restrict__ q_embed, float* __restrict__ out){
  const int b = blockIdx.x, tid = threadIdx.x, lane = tid & 63, jr = tid >> 6;
  __shared__ float s2_lds[64];
  __shared__ float wq_lds[64*65];
  __shared__ float wor_lds[64*65];
  if (tid < 64) s2_lds[tid] = s2f_tab[b*64 + tid];
  #pragma unroll
  for (int j0 = 0; j0 < 16; ++j0){
    int j = j0*4 + jr;
    wq_lds[j*65 + lane]  = w_qr[j*64 + lane];
    wor_lds[j*65 + lane] = w_or[j*64 + lane];
  }
  __syncthreads();
  if (tid >= 64) return;

  float vals[16];
  #pragma unroll
  for (int j = 0; j < 16; ++j){
    int tk = seq[b*1024 + j*64 + lane];
    vals[j] = s2_lds[tk];
  }
  int sel[6];
  #pragma unroll
  for (int r = 0; r < 6; ++r){
    float bv = -1.f; int bi = 1 << 30;
    #pragma unroll
    for (int j = 0; j < 16; ++j){
      float v = vals[j]; int i = (j << 6) | lane;
      if (v > bv || (v == bv && i < bi)){ bv = v; bi = i; }
    }
    #pragma unroll
    for (int o = 32; o; o >>= 1){
      float ov = __shfl_xor(bv, o, 64);
      int   oi = __shfl_xor(bi, o, 64);
      if (ov > bv || (ov == bv && oi < bi)){ bv = ov; bi = oi; }
    }
    sel[r] = bi;
    int jw = bi >> 6, lw = bi & 63;
    if (lane == lw){
      #pragma unroll
      for (int j = 0; j < 16; ++j) if (j == jw) vals[j] = -1.f;
    }
  }

  float mem[6];
  #pragma unroll
  for (int s = 0; s < 6; ++s){
    int tk = seq[b*1024 + sel[s]];
    mem[s] = hidden_tab[(b*64 + tk)*64 + lane];
  }
  float qe = q_embed[query[b]*64 + lane];
  float qv0 = b_qr[lane], qv1 = 0.f, qv2 = 0.f, qv3 = 0.f;
  #pragma unroll
  for (int k = 0; k < 64; k += 4){
    qv0 += wq_lds[lane*65 + k]     * __shfl(qe, k, 64);
    qv1 += wq_lds[lane*65 + k + 1] * __shfl(qe, k+1, 64);
    qv2 += wq_lds[lane*65 + k + 2] * __shfl(qe, k+2, 64);
    qv3 += wq_lds[lane*65 + k + 3] * __shfl(qe, k+3, 64);
  }
  float qv = (qv0 + qv1) + (qv2 + qv3);
  float scv[6];
  #pragma unroll
  for (int s = 0; s < 6; ++s) scv[s] = wsum(qv * mem[s]) * 0.125f;
  float mx = scv[0];
  #pragma unroll
  for (int s = 1; s < 6; ++s) mx = fmaxf(mx, scv[s]);
  float e[6], se = 0.f;
  #pragma unroll
  for (int s = 0; s < 6; ++s){ e[s] = __expf(scv[s] - mx); se += e[s]; }
  float ctx = 0.f;
  #pragma unroll
  for (int s = 0; s < 6; ++s) ctx += (e[s] / se) * mem[s];
  float l0 = b_or[lane], l1 = 0.f, l2 = 0.f, l3 = 0.f;
  #pragma unroll
  for (int k = 0; k < 64; k += 4){
    l0 += wor_lds[lane*65 + k]     * __shfl(ctx, k, 64);
    l1 += wor_lds[lane*65 + k + 1] * __shfl(ctx, k+1, 64);
    l2 += wor_lds[lane*65 + k + 2] * __shfl(ctx, k+2, 64);
    l3 += wor_lds[lane*65 + k + 3] * __shfl(ctx, k+3, 64);
  }
  float lg = (l0 + l1) + (l2 + l3);
  float lm = wmax(lg);
  float ss = wsum(__expf(lg - lm));
  float lt = __shfl(lg, target[b], 64);
  if (lane == 0) atomicAdd(out, -(lt - lm - __logf(ss)) * 0.015625f);
}

// ---------------------------------------------------------------------------
extern "C" void kernel_launch(void* const* d_in, const int* in_sizes, int n_in,
                              void* d_out, int out_size, void* d_ws, size_t ws_size,
                              hipStream_t stream){
  const int*   seq     = (const int*)  d_in[0];
  const int*   query   = (const int*)  d_in[1];
  const int*   target  = (const int*)  d_in[2];
  const float* embed   = (const float*)d_in[3];
  const float* wqkv    = (const float*)d_in[4];
  const float* bqkv    = (const float*)d_in[5];
  const float* wo_attn = (const float*)d_in[6];
  const float* bo_attn = (const float*)d_in[7];
  const float* w_ff1   = (const float*)d_in[8];
  const float* b_ff1   = (const float*)d_in[9];
  const float* w_ff2   = (const float*)d_in[10];
  const float* b_ff2   = (const float*)d_in[11];
  const float* g1      = (const float*)d_in[12];
  const float* be1     = (const float*)d_in[13];
  const float* g2      = (const float*)d_in[14];
  const float* be2     = (const float*)d_in[15];
  const float* w_s1    = (const float*)d_in[16];
  const float* b_s1    = (const float*)d_in[17];
  const float* w_s2    = (const float*)d_in[18];
  const float* b_s2    = (const float*)d_in[19];
  const float* w_qr    = (const float*)d_in[20];
  const float* b_qr    = (const float*)d_in[21];
  const float* w_or    = (const float*)d_in[22];
  const float* b_or    = (const float*)d_in[23];
  const float* q_embed = (const float*)d_in[24];

  float* ws = (float*)d_ws;
  float* qkv_tab    = ws;                 // 64*192
  float* cnt_f      = ws + 12288;         // 64*64
  float* hidden_tab = ws + 16384;         // 64*64*64
  float* s2f_tab    = ws + 278528;        // 64*64

  float* out = (float*)d_out;

  k_prep<<<64, 1024, 0, stream>>>(seq, embed, wqkv, bqkv, qkv_tab, cnt_f, out);
  k_enc<<<256, 512, 0, stream>>>(qkv_tab, cnt_f, embed, wo_attn, bo_attn,
                                 w_ff1, b_ff1, w_ff2, b_ff2, g1, be1, g2, be2,
                                 w_s1, b_s1, w_s2, b_s2, hidden_tab, s2f_tab);
  k_sel<<<64, 256, 0, stream>>>(seq, query, target, hidden_tab, s2f_tab,
                                w_qr, b_qr, w_or, b_or, q_embed, out);
}

// Round 7
// 131.009 us; speedup vs baseline: 1.4425x; 1.4425x over previous
//
#include <hip/hip_runtime.h>

#define DEV __device__ __forceinline__

DEV int   f2i(float v){ return __builtin_bit_cast(int, v); }
DEV float i2f(int v){ return __builtin_bit_cast(float, v); }
DEV float blane(float v, int l){ return i2f(__builtin_amdgcn_readlane(f2i(v), l)); }

template<int C, int RM> DEV float dpp_add_m(float v){
  return v + i2f(__builtin_amdgcn_update_dpp(0, f2i(v), C, RM, 0xF, true));
}
template<int C, int RM> DEV float dpp_max_m(float v){
  return fmaxf(v, i2f(__builtin_amdgcn_update_dpp(0, f2i(v), C, RM, 0xF, true)));
}
// all-DPP wave64 reduction (no LDS ops); lane 63 holds total -> one readlane.
DEV float wred_sum(float v){
  v = dpp_add_m<0xB1,0xF>(v); v = dpp_add_m<0x4E,0xF>(v);
  v = dpp_add_m<0x141,0xF>(v); v = dpp_add_m<0x140,0xF>(v);
  v = dpp_add_m<0x142,0xA>(v);   // row_bcast15 -> rows 1,3
  v = dpp_add_m<0x143,0xC>(v);   // row_bcast31 -> rows 2,3
  return blane(v, 63);
}
DEV float wred_max(float v){
  v = dpp_max_m<0xB1,0xF>(v); v = dpp_max_m<0x4E,0xF>(v);
  v = dpp_max_m<0x141,0xF>(v); v = dpp_max_m<0x140,0xF>(v);
  v = dpp_max_m<0x142,0xA>(v);
  v = dpp_max_m<0x143,0xC>(v);
  return blane(v, 63);
}

// shuffle helpers (k_sel)
DEV float wsum(float v){
  #pragma unroll
  for (int o = 32; o; o >>= 1) v += __shfl_xor(v, o, 64);
  return v;
}
DEV float wmax(float v){
  #pragma unroll
  for (int o = 32; o; o >>= 1) v = fmaxf(v, __shfl_xor(v, o, 64));
  return v;
}

// ---------------------------------------------------------------------------
// K1: per-batch token histogram + per-token QKV projection table.
// Block i: histogram of seq[i,:] (batch role) AND qkv row for token-id i
// (token role; B == V == 64). qkv_tab[tok][0:64]=q,[64:128]=k,[128:192]=v.
// Block 0 zeroes the output accumulator.
// ---------------------------------------------------------------------------
__global__ __launch_bounds__(1024) void k_prep(
    const int* __restrict__ seq, const float* __restrict__ embed,
    const float* __restrict__ wqkv, const float* __restrict__ bqkv,
    float* __restrict__ qkv_tab, float* __restrict__ cnt_f,
    float* __restrict__ out){
  const int b = blockIdx.x, tid = threadIdx.x;
  if (b == 0 && tid == 0) out[0] = 0.f;
  __shared__ float emb[64];
  __shared__ int hh[64];
  if (tid < 64){ emb[tid] = embed[b*64 + tid]; hh[tid] = 0; }
  __syncthreads();
  atomicAdd(&hh[seq[b*1024 + tid]], 1);
  if (tid < 192){
    const float4* w4 = (const float4*)(wqkv + tid*64);
    float a0 = bqkv[tid], a1 = 0.f, a2 = 0.f, a3 = 0.f;
    #pragma unroll
    for (int k = 0; k < 16; k += 4){
      float4 wa = w4[k],   wb = w4[k+1], wc = w4[k+2], wd = w4[k+3];
      a0 += wa.x*emb[4*k]    + wa.y*emb[4*k+1]  + wa.z*emb[4*k+2]  + wa.w*emb[4*k+3];
      a1 += wb.x*emb[4*k+4]  + wb.y*emb[4*k+5]  + wb.z*emb[4*k+6]  + wb.w*emb[4*k+7];
      a2 += wc.x*emb[4*k+8]  + wc.y*emb[4*k+9]  + wc.z*emb[4*k+10] + wc.w*emb[4*k+11];
      a3 += wd.x*emb[4*k+12] + wd.y*emb[4*k+13] + wd.z*emb[4*k+14] + wd.w*emb[4*k+15];
    }
    qkv_tab[b*192 + tid] = (a0+a1)+(a2+a3);
  }
  __syncthreads();
  if (tid < 64) cnt_f[b*64 + tid] = (float)hh[tid];
}

// ---------------------------------------------------------------------------
// K2a: attention phase. hidden[b,l] depends only on (b, seq[b,l]) -> compute
// per (batch, token-type). Grid: 512 = (b = blk>>3, oct = blk&7).
// Block: 512 thr = 8 waves, ONE token per wave (tok = oct*8 + wave).
// LDS 48KB (K,V^T,WO) -> 3 blocks/CU capacity, 2 resident -> 4 waves/SIMD.
// Writes xn (post-LN1) to xn_tab.
// ---------------------------------------------------------------------------
__global__ __launch_bounds__(512, 4) void k_attn(
    const float* __restrict__ qkv_tab, const float* __restrict__ cnt_f,
    const float* __restrict__ embed,
    const float* __restrict__ wo_attn, const float* __restrict__ bo_attn,
    const float* __restrict__ g1, const float* __restrict__ be1,
    float* __restrict__ xn_tab){
  const int b = blockIdx.x >> 3, oct = blockIdx.x & 7;
  const int tid = threadIdx.x, w = tid >> 6, lane = tid & 63;

  __shared__ float4 k4 [64*16];    // K rows (token-major), swizzled slots
  __shared__ float4 v4t[64*16];    // V^T rows (dim-major), swizzled slots
  __shared__ float4 wo4[64*16];
  __shared__ float  cnt_lds[64];

  const float4* qkv4 = (const float4*)qkv_tab;
  const float4* wo_4 = (const float4*)wo_attn;
  float* v4f = (float*)v4t;

  #pragma unroll
  for (int ii = 0; ii < 2; ++ii){
    int i = tid + ii*512;
    int r = i >> 4, c4 = i & 15, s = c4 ^ (r & 15);
    k4 [r*16 + s] = qkv4[r*48 + 16 + c4];
    wo4[r*16 + s] = wo_4[i];
    float4 vv = qkv4[r*48 + 32 + c4];
    int d0 = 4*c4;
    v4f[(d0  )*64 + 4*((r>>2) ^ ((d0  )&15)) + (r&3)] = vv.x;
    v4f[(d0+1)*64 + 4*((r>>2) ^ ((d0+1)&15)) + (r&3)] = vv.y;
    v4f[(d0+2)*64 + 4*((r>>2) ^ ((d0+2)&15)) + (r&3)] = vv.z;
    v4f[(d0+3)*64 + 4*((r>>2) ^ ((d0+3)&15)) + (r&3)] = vv.w;
  }
  if (tid < 64) cnt_lds[tid] = cnt_f[b*64 + tid];
  __syncthreads();

  const int   tok = oct*8 + w;
  const int   sw = lane & 15;
  const float cme  = cnt_lds[lane];
  const bool  pres = cme > 0.f;
  const float sc = 0.17677669529663687f;  // 1/sqrt(32)
  const float g1v = g1[lane], be1v = be1[lane];
  const float bov = bo_attn[lane];

  // ---- scores: lane = key token ----
  float q0 = qkv_tab[tok*192 + lane];
  float sA = 0.f, sB = 0.f;
  #pragma unroll
  for (int c4 = 0; c4 < 16; ++c4){
    float4 kk = k4[lane*16 + (c4 ^ sw)];
    #pragma unroll
    for (int j = 0; j < 4; ++j){
      const int d = 4*c4 + j;
      float ke = (j==0)?kk.x:(j==1)?kk.y:(j==2)?kk.z:kk.w;
      float b0 = blane(q0, d);
      if (d < 32) sA += b0*ke; else sB += b0*ke;
    }
  }
  // ---- count-weighted softmax over token types ----
  float s0 = sA*sc, s1 = sB*sc;
  float m0 = wred_max(pres ? s0 : -1e30f);
  float m1 = wred_max(pres ? s1 : -1e30f);
  float p0 = pres ? cme*__expf(s0 - m0) : 0.f;
  float p1 = pres ? cme*__expf(s1 - m1) : 0.f;
  float d0v = wred_sum(p0);
  float d1v = wred_sum(p1);
  // ---- o[lane] = sum_t' p[h(lane)][t'] * v[t'][lane] ----
  float o = 0.f;
  #pragma unroll
  for (int c4 = 0; c4 < 16; ++c4){
    float4 vv = v4t[lane*16 + (c4 ^ sw)];
    #pragma unroll
    for (int j = 0; j < 4; ++j){
      const int tp = 4*c4 + j;
      float ve = (j==0)?vv.x:(j==1)?vv.y:(j==2)?vv.z:vv.w;
      float a0 = blane(p0, tp), a1 = blane(p1, tp);
      o += (lane < 32 ? a0 : a1) * ve;
    }
  }
  o /= (lane < 32 ? d0v : d1v);
  // ---- out-proj ----
  float aT = bov;
  #pragma unroll
  for (int c4 = 0; c4 < 16; ++c4){
    float4 ww = wo4[lane*16 + (c4 ^ sw)];
    #pragma unroll
    for (int j = 0; j < 4; ++j){
      const int k = 4*c4 + j;
      float we = (j==0)?ww.x:(j==1)?ww.y:(j==2)?ww.z:ww.w;
      aT += we*blane(o, k);
    }
  }
  // ---- residual + LN1 ----
  float x = embed[tok*64 + lane] + aT;
  float mu = wred_sum(x) * 0.015625f;
  float xm = x - mu;
  float var = wred_sum(xm*xm) * 0.015625f;
  float xn = xm * rsqrtf(var + 1e-5f) * g1v + be1v;
  xn_tab[(b*64 + tok)*64 + lane] = xn;
}

// ---------------------------------------------------------------------------
// K2b: FFN phase. Grid: 512 = (b, oct); 8 waves, one token per wave.
// LDS 64KB (FF1,FF2) -> 2 blocks/CU -> 4 waves/SIMD.
// Reads xn_tab, writes hidden_tab + s2f_tab.
// ---------------------------------------------------------------------------
__global__ __launch_bounds__(512, 4) void k_ffn(
    const float* __restrict__ xn_tab,
    const float* __restrict__ w_ff1, const float* __restrict__ b_ff1,
    const float* __restrict__ w_ff2, const float* __restrict__ b_ff2,
    const float* __restrict__ g2, const float* __restrict__ be2,
    const float* __restrict__ w_s1, const float* __restrict__ b_s1,
    const float* __restrict__ w_s2, const float* __restrict__ b_s2,
    float* __restrict__ hidden_tab, float* __restrict__ s2f_tab){
  const int b = blockIdx.x >> 3, oct = blockIdx.x & 7;
  const int tid = threadIdx.x, w = tid >> 6, lane = tid & 63;

  __shared__ float4 f14[128*16];
  __shared__ float4 f24[64*32];

  const float4* f1_4 = (const float4*)w_ff1;
  const float4* f2_4 = (const float4*)w_ff2;

  #pragma unroll
  for (int ii = 0; ii < 4; ++ii){
    int i = tid + ii*512;
    int r1 = i >> 4, c41 = i & 15;
    f14[r1*16 + (c41 ^ (r1 & 15))] = f1_4[i];
    int r2 = i >> 5, c42 = i & 31;
    f24[r2*32 + (c42 ^ (r2 & 15))] = f2_4[i];
  }
  __syncthreads();

  const int   tok = oct*8 + w;
  const int   sw = lane & 15;
  const float g2v = g2[lane], be2v = be2[lane];
  const float bf2v = b_ff2[lane];
  const float bf1a = b_ff1[lane], bf1b = b_ff1[64 + lane];
  const float ws1v = w_s1[lane], ws2v = w_s2[lane];
  const float bs1 = b_s1[0], bs2 = b_s2[0];

  float xn = xn_tab[(b*64 + tok)*64 + lane];
  // ---- FF1 + ReLU ----
  float y0 = bf1a, y1 = bf1b;
  #pragma unroll
  for (int c4 = 0; c4 < 16; ++c4){
    float4 wA = f14[lane*16 + (c4 ^ sw)];
    float4 wB = f14[(lane+64)*16 + (c4 ^ sw)];
    #pragma unroll
    for (int j = 0; j < 4; ++j){
      const int k = 4*c4 + j;
      float wa = (j==0)?wA.x:(j==1)?wA.y:(j==2)?wA.z:wA.w;
      float wb = (j==0)?wB.x:(j==1)?wB.y:(j==2)?wB.z:wB.w;
      float x0 = blane(xn, k);
      y0 += wa*x0;
      y1 += wb*x0;
    }
  }
  y0 = fmaxf(y0, 0.f); y1 = fmaxf(y1, 0.f);
  // ---- FF2 ----
  float z = bf2v;
  #pragma unroll
  for (int c4 = 0; c4 < 32; ++c4){
    float4 ww = f24[lane*32 + (c4 ^ sw)];
    #pragma unroll
    for (int j = 0; j < 4; ++j){
      const int jj = 4*c4 + j;
      float we = (j==0)?ww.x:(j==1)?ww.y:(j==2)?ww.z:ww.w;
      if (jj < 64) z += we*blane(y0, jj);
      else         z += we*blane(y1, jj-64);
    }
  }
  // ---- residual + LN2 + gates + store ----
  float r = xn + z;
  float mu2 = wred_sum(r) * 0.015625f;
  float rm = r - mu2;
  float var2 = wred_sum(rm*rm) * 0.015625f;
  float hid = rm * rsqrtf(var2 + 1e-5f) * g2v + be2v;
  float t1 = wred_sum(hid * ws1v) + bs1;
  float t2 = wred_sum(hid * ws2v) + bs2;
  float sg1 = 1.f / (1.f + __expf(-t1));
  float sg2 = 1.f / (1.f + __expf(-t2));
  float s2f = (sg1 > 0.5f) ? sg2 : 0.f;
  hidden_tab[(b*64 + tok)*64 + lane] = hid;
  if (lane == 0) s2f_tab[b*64 + tok] = s2f;
}

// ---------------------------------------------------------------------------
// K3: per-batch top-6 selection (JAX top_k: value desc, index asc tie-break),
// memory reader, cross-entropy, atomic mean into out.
// 64 blocks x 256 threads: 4 waves stage weights cooperatively, wave 0 computes.
// ---------------------------------------------------------------------------
__global__ __launch_bounds__(256) void k_sel(
    const int* __restrict__ seq, const int* __restrict__ query,
    const int* __restrict__ target,
    const float* __restrict__ hidden_tab, const float* __restrict__ s2f_tab,
    const float* __restrict__ w_qr, const float* __restrict__ b_qr,
    const float* __restrict__ w_or, const float* __restrict__ b_or,
    const float* __restrict__ q_embed, float* __restrict__ out){
  const int b = blockIdx.x, tid = threadIdx.x, lane = tid & 63, jr = tid >> 6;
  __shared__ float s2_lds[64];
  __shared__ float wq_lds[64*65];
  __shared__ float wor_lds[64*65];
  if (tid < 64) s2_lds[tid] = s2f_tab[b*64 + tid];
  #pragma unroll
  for (int j0 = 0; j0 < 16; ++j0){
    int j = j0*4 + jr;
    wq_lds[j*65 + lane]  = w_qr[j*64 + lane];
    wor_lds[j*65 + lane] = w_or[j*64 + lane];
  }
  __syncthreads();
  if (tid >= 64) return;

  float vals[16];
  #pragma unroll
  for (int j = 0; j < 16; ++j){
    int tk = seq[b*1024 + j*64 + lane];
    vals[j] = s2_lds[tk];
  }
  int sel[6];
  #pragma unroll
  for (int r = 0; r < 6; ++r){
    float bv = -1.f; int bi = 1 << 30;
    #pragma unroll
    for (int j = 0; j < 16; ++j){
      float v = vals[j]; int i = (j << 6) | lane;
      if (v > bv || (v == bv && i < bi)){ bv = v; bi = i; }
    }
    #pragma unroll
    for (int o = 32; o; o >>= 1){
      float ov = __shfl_xor(bv, o, 64);
      int   oi = __shfl_xor(bi, o, 64);
      if (ov > bv || (ov == bv && oi < bi)){ bv = ov; bi = oi; }
    }
    sel[r] = bi;
    int jw = bi >> 6, lw = bi & 63;
    if (lane == lw){
      #pragma unroll
      for (int j = 0; j < 16; ++j) if (j == jw) vals[j] = -1.f;
    }
  }

  float mem[6];
  #pragma unroll
  for (int s = 0; s < 6; ++s){
    int tk = seq[b*1024 + sel[s]];
    mem[s] = hidden_tab[(b*64 + tk)*64 + lane];
  }
  float qe = q_embed[query[b]*64 + lane];
  float qv0 = b_qr[lane], qv1 = 0.f, qv2 = 0.f, qv3 = 0.f;
  #pragma unroll
  for (int k = 0; k < 64; k += 4){
    qv0 += wq_lds[lane*65 + k]     * __shfl(qe, k, 64);
    qv1 += wq_lds[lane*65 + k + 1] * __shfl(qe, k+1, 64);
    qv2 += wq_lds[lane*65 + k + 2] * __shfl(qe, k+2, 64);
    qv3 += wq_lds[lane*65 + k + 3] * __shfl(qe, k+3, 64);
  }
  float qv = (qv0 + qv1) + (qv2 + qv3);
  float scv[6];
  #pragma unroll
  for (int s = 0; s < 6; ++s) scv[s] = wsum(qv * mem[s]) * 0.125f;
  float mx = scv[0];
  #pragma unroll
  for (int s = 1; s < 6; ++s) mx = fmaxf(mx, scv[s]);
  float e[6], se = 0.f;
  #pragma unroll
  for (int s = 0; s < 6; ++s){ e[s] = __expf(scv[s] - mx); se += e[s]; }
  float ctx = 0.f;
  #pragma unroll
  for (int s = 0; s < 6; ++s) ctx += (e[s] / se) * mem[s];
  float l0 = b_or[lane], l1 = 0.f, l2 = 0.f, l3 = 0.f;
  #pragma unroll
  for (int k = 0; k < 64; k += 4){
    l0 += wor_lds[lane*65 + k]     * __shfl(ctx, k, 64);
    l1 += wor_lds[lane*65 + k + 1] * __shfl(ctx, k+1, 64);
    l2 += wor_lds[lane*65 + k + 2] * __shfl(ctx, k+2, 64);
    l3 += wor_lds[lane*65 + k + 3] * __shfl(ctx, k+3, 64);
  }
  float lg = (l0 + l1) + (l2 + l3);
  float lm = wmax(lg);
  float ss = wsum(__expf(lg - lm));
  float lt = __shfl(lg, target[b], 64);
  if (lane == 0) atomicAdd(out, -(lt - lm - __logf(ss)) * 0.015625f);
}

// ---------------------------------------------------------------------------
extern "C" void kernel_launch(void* const* d_in, const int* in_sizes, int n_in,
                              void* d_out, int out_size, void* d_ws, size_t ws_size,
                              hipStream_t stream){
  const int*   seq     = (const int*)  d_in[0];
  const int*   query   = (const int*)  d_in[1];
  const int*   target  = (const int*)  d_in[2];
  const float* embed   = (const float*)d_in[3];
  const float* wqkv    = (const float*)d_in[4];
  const float* bqkv    = (const float*)d_in[5];
  const float* wo_attn = (const float*)d_in[6];
  const float* bo_attn = (const float*)d_in[7];
  const float* w_ff1   = (const float*)d_in[8];
  const float* b_ff1   = (const float*)d_in[9];
  const float* w_ff2   = (const float*)d_in[10];
  const float* b_ff2   = (const float*)d_in[11];
  const float* g1      = (const float*)d_in[12];
  const float* be1     = (const float*)d_in[13];
  const float* g2      = (const float*)d_in[14];
  const float* be2     = (const float*)d_in[15];
  const float* w_s1    = (const float*)d_in[16];
  const float* b_s1    = (const float*)d_in[17];
  const float* w_s2    = (const float*)d_in[18];
  const float* b_s2    = (const float*)d_in[19];
  const float* w_qr    = (const float*)d_in[20];
  const float* b_qr    = (const float*)d_in[21];
  const float* w_or    = (const float*)d_in[22];
  const float* b_or    = (const float*)d_in[23];
  const float* q_embed = (const float*)d_in[24];

  float* ws = (float*)d_ws;
  float* qkv_tab    = ws;                 // 64*192
  float* cnt_f      = ws + 12288;         // 64*64
  float* hidden_tab = ws + 16384;         // 64*64*64
  float* s2f_tab    = ws + 278528;        // 64*64
  float* xn_tab     = ws + 282624;        // 64*64*64

  float* out = (float*)d_out;

  k_prep<<<64, 1024, 0, stream>>>(seq, embed, wqkv, bqkv, qkv_tab, cnt_f, out);
  k_attn<<<512, 512, 0, stream>>>(qkv_tab, cnt_f, embed, wo_attn, bo_attn,
                                  g1, be1, xn_tab);
  k_ffn<<<512, 512, 0, stream>>>(xn_tab, w_ff1, b_ff1, w_ff2, b_ff2,
                                 g2, be2, w_s1, b_s1, w_s2, b_s2,
                                 hidden_tab, s2f_tab);
  k_sel<<<64, 256, 0, stream>>>(seq, query, target, hidden_tab, s2f_tab,
                                w_qr, b_qr, w_or, b_or, q_embed, out);
}